// Round 10
// baseline (339.644 us; speedup 1.0000x reference)
//
#include <hip/hip_runtime.h>

#define H_DIM 128

typedef __attribute__((ext_vector_type(8))) short short8v;
typedef __attribute__((ext_vector_type(4))) float f32x4;

__device__ __forceinline__ ushort f2bf(float f) {
  unsigned u = __builtin_bit_cast(unsigned, f);
  u += 0x7fffu + ((u >> 16) & 1u);  // RNE
  return (ushort)(u >> 16);
}
__device__ __forceinline__ float bflo(unsigned u) {
  return __builtin_bit_cast(float, u << 16);
}
__device__ __forceinline__ float bfhi(unsigned u) {
  return __builtin_bit_cast(float, u & 0xffff0000u);
}
__device__ __forceinline__ short8v pack_bf8(float4 a0, float4 a1) {
  short8v af;
  af[0] = (short)f2bf(a0.x);
  af[1] = (short)f2bf(a0.y);
  af[2] = (short)f2bf(a0.z);
  af[3] = (short)f2bf(a0.w);
  af[4] = (short)f2bf(a1.x);
  af[5] = (short)f2bf(a1.y);
  af[6] = (short)f2bf(a1.z);
  af[7] = (short)f2bf(a1.w);
  return af;
}

// ===========================================================================
// Fused: weight cast/transpose (blocks 0..191) + concatenated histogram.
// Histogram atomic's return value = edge rank (atomic-free permute later).
// Wt[m][j][k] = W[k][j]; m=0: W_r[0:128], m=1: W_r[128:256], m=2: W_p.
// ===========================================================================
__global__ __launch_bounds__(256) void histcast_k(
    const float* __restrict__ W_r, const float* __restrict__ W_p,
    ushort* __restrict__ Wt, const int* __restrict__ d0,
    const int* __restrict__ d1, const int* __restrict__ d2,
    int* __restrict__ ro, int* __restrict__ rank, int n0, int n1, int n2,
    int NRn) {
  int bid = blockIdx.x;
  if (bid < 192) {
    int i = bid * 256 + threadIdx.x;
    int m = i >> 14;
    int j = (i >> 7) & 127;
    int k = i & 127;
    float v = (m == 0)   ? W_r[k * 128 + j]
              : (m == 1) ? W_r[(128 + k) * 128 + j]
                         : W_p[k * 128 + j];
    Wt[i] = f2bf(v);
  } else {
    int e = (bid - 192) * 256 + threadIdx.x;
    int slot;
    if (e < n0)
      slot = d0[e];
    else if (e < n0 + n1)
      slot = NRn + d1[e - n0];
    else if (e < n0 + n1 + n2)
      slot = 2 * NRn + d2[e - n0 - n1];
    else
      return;
    rank[e] = atomicAdd(&ro[slot], 1);
  }
}

// ===========================================================================
// scan1 + folded block-sum scan: per-block (2048 elems) exclusive scan
// in-place; block sums -> bsums; the LAST finishing block (threadfence +
// atomic counter) scans bsums into bscan. Consumers compute the global
// offset as ro[slot] + bscan[slot>>11].
// ===========================================================================
__global__ __launch_bounds__(256) void scan1_k(int* __restrict__ a, int n,
                                               int* __restrict__ bsums,
                                               int* __restrict__ bscan,
                                               int* __restrict__ cnt, int nb) {
  __shared__ int ts[256];
  __shared__ bool amlast;
  int t = threadIdx.x;
  int base = blockIdx.x * 2048 + t * 8;
  int v[8];
  int s = 0;
#pragma unroll
  for (int k = 0; k < 8; ++k) {
    v[k] = (base + k < n) ? a[base + k] : 0;
    s += v[k];
  }
  ts[t] = s;
  __syncthreads();
  for (int off = 1; off < 256; off <<= 1) {
    int x = (t >= off) ? ts[t - off] : 0;
    __syncthreads();
    ts[t] += x;
    __syncthreads();
  }
  if (t == 0) bsums[blockIdx.x] = ts[255];
  int run = (t == 0) ? 0 : ts[t - 1];
#pragma unroll
  for (int k = 0; k < 8; ++k) {
    int x = v[k];
    if (base + k < n) a[base + k] = run;
    run += x;
  }
  // last-block-done: scan bsums -> bscan
  __threadfence();
  __syncthreads();
  if (t == 0) {
    int old = atomicAdd(cnt, 1);
    amlast = (old == gridDim.x - 1);
  }
  __syncthreads();
  if (amlast) {
    __threadfence();
    int bv = (t < nb) ? bsums[t] : 0;
    ts[t] = bv;
    __syncthreads();
    for (int off = 1; off < 256; off <<= 1) {
      int x = (t >= off) ? ts[t - off] : 0;
      __syncthreads();
      ts[t] += x;
      __syncthreads();
    }
    if (t < nb) bscan[t] = (t == 0) ? 0 : ts[t - 1];
  }
}

// ===========================================================================
// Fused: dense GEMM (M-tile 128, two row-tiles per wave SHARING each
// B-fragment -> 16 MFMA per 8 ds_read_b128) + atomic-free edge permute,
// proportionally interleaved. 32KB LDS keeps occupancy.
// ===========================================================================
__global__ __launch_bounds__(256) void permgemm_k(
    const float* __restrict__ rf, const float* __restrict__ pf,
    const ushort* __restrict__ Wt, ushort* __restrict__ Y1,
    ushort* __restrict__ Y2, ushort* __restrict__ Yp,
    const int* __restrict__ s0a, const int* __restrict__ d0a,
    const int* __restrict__ s1a, const int* __restrict__ d1a,
    const int* __restrict__ s2a, const int* __restrict__ d2a,
    const int* __restrict__ ro, const int* __restrict__ bscan,
    const int* __restrict__ rank, int* __restrict__ es, int nb1, int nb2,
    int M1, int M2, int n0, int n1, int n2, int NRn, int ng, int np) {
  __shared__ float lds_f[8192];  // 32KB
  long T = (long)ng + np;
  long b = blockIdx.x;
  int g_before = (int)((b * ng) / T);
  int g_incl = (int)(((b + 1) * ng) / T);
  bool do_gemm = g_incl > g_before;
  int idx = do_gemm ? g_before : (int)(b - g_before);

  if (!do_gemm) {
    long e = (long)idx * 256 + threadIdx.x;
    int src, slot;
    if (e < n0) {
      slot = d0a[e];
      src = s0a[e];
    } else if (e < n0 + n1) {
      long i = e - n0;
      slot = NRn + d1a[i];
      src = s1a[i];
    } else if (e < n0 + n1 + n2) {
      long i = e - n0 - n1;
      slot = 2 * NRn + d2a[i];
      src = s2a[i];
    } else
      return;
    es[ro[slot] + bscan[slot >> 11] + rank[e]] = src;
    return;
  }

  ushort* wl = (ushort*)lds_f;
  const float* X;
  ushort* Y;
  const ushort* Wg;
  int M, row0;
  if (idx < nb1) {
    X = rf; Y = Y1; Wg = Wt; M = M1; row0 = idx * 128;
  } else if (idx < nb1 + nb2) {
    X = pf; Y = Y2; Wg = Wt + 16384; M = M2; row0 = (idx - nb1) * 128;
  } else {
    X = rf; Y = Yp; Wg = Wt + 32768; M = M1; row0 = (idx - nb1 - nb2) * 128;
  }

  int tid = threadIdx.x;
  {  // stage W -> LDS, XOR swizzle on 8-ushort granularity
    const uint4* src = (const uint4*)Wg;
    for (int i = tid; i < 2048; i += 256) {
      int j = i >> 4;
      int k8 = (i & 15) * 8;
      int kk = k8 ^ ((j & 7) << 3);
      *(uint4*)&wl[j * 128 + kk] = src[i];
    }
  }
  __syncthreads();

  int lane = tid & 63;
  int wv = tid >> 6;
  int l15 = lane & 15;
  int kq = lane >> 4;
  int rowl = wv * 16 + l15;
  int g0 = row0 + rowl;
  int g1 = row0 + 64 + rowl;
  int gc0 = g0 < M ? g0 : M - 1;
  int gc1 = g1 < M ? g1 : M - 1;

  f32x4 acc0[8], acc1[8];
#pragma unroll
  for (int t = 0; t < 8; ++t) {
    f32x4 z = {0.f, 0.f, 0.f, 0.f};
    acc0[t] = z;
    acc1[t] = z;
  }

#pragma unroll
  for (int ks = 0; ks < 4; ++ks) {
    int k0 = ks * 32;
    const float* ap0 = X + (long)gc0 * H_DIM + k0 + kq * 8;
    const float* ap1 = X + (long)gc1 * H_DIM + k0 + kq * 8;
    float4 a00 = *(const float4*)ap0;
    float4 a01 = *(const float4*)(ap0 + 4);
    float4 a10 = *(const float4*)ap1;
    float4 a11 = *(const float4*)(ap1 + 4);
    short8v af0 = pack_bf8(a00, a01);
    short8v af1 = pack_bf8(a10, a11);
#pragma unroll
    for (int nt = 0; nt < 8; ++nt) {
      int j = nt * 16 + l15;
      int kk = (k0 + kq * 8) ^ ((j & 7) << 3);
      short8v bf = *(const short8v*)&wl[j * 128 + kk];
      acc0[nt] =
          __builtin_amdgcn_mfma_f32_16x16x32_bf16(af0, bf, acc0[nt], 0, 0, 0);
      acc1[nt] =
          __builtin_amdgcn_mfma_f32_16x16x32_bf16(af1, bf, acc1[nt], 0, 0, 0);
    }
  }

  // ---- epilogue pass 0: rows [row0, row0+64) ----
  __syncthreads();
#pragma unroll
  for (int nt = 0; nt < 8; ++nt) {
#pragma unroll
    for (int r = 0; r < 4; ++r) {
      int rl = wv * 16 + kq * 4 + r;
      int col = (nt * 16 + l15) ^ (kq << 4);
      lds_f[rl * 128 + col] = acc0[nt][r];
    }
  }
  __syncthreads();
  for (int i = tid; i < 2048; i += 256) {
    int flat = i * 4;
    int r = flat >> 7;
    int cc = flat & 127;
    int sw = ((r >> 2) & 3) << 4;
    int gr = row0 + r;
    if (gr < M) {
      float4 v = *(const float4*)&lds_f[r * 128 + (cc ^ sw)];
      ushort4 o;
      o.x = f2bf(v.x);
      o.y = f2bf(v.y);
      o.z = f2bf(v.z);
      o.w = f2bf(v.w);
      *(ushort4*)&Y[(long)gr * H_DIM + cc] = o;
    }
  }
  // ---- epilogue pass 1: rows [row0+64, row0+128) ----
  __syncthreads();
#pragma unroll
  for (int nt = 0; nt < 8; ++nt) {
#pragma unroll
    for (int r = 0; r < 4; ++r) {
      int rl = wv * 16 + kq * 4 + r;
      int col = (nt * 16 + l15) ^ (kq << 4);
      lds_f[rl * 128 + col] = acc1[nt][r];
    }
  }
  __syncthreads();
  for (int i = tid; i < 2048; i += 256) {
    int flat = i * 4;
    int r = flat >> 7;
    int cc = flat & 127;
    int sw = ((r >> 2) & 3) << 4;
    int gr = row0 + 64 + r;
    if (gr < M) {
      float4 v = *(const float4*)&lds_f[r * 128 + (cc ^ sw)];
      ushort4 o;
      o.x = f2bf(v.x);
      o.y = f2bf(v.y);
      o.z = f2bf(v.z);
      o.w = f2bf(v.w);
      *(ushort4*)&Y[(long)gr * H_DIM + cc] = o;
    }
  }
}

// ===========================================================================
// Gather: 16 lanes/row, uint4 (8 bf16)/lane. Router rows run a FUSED
// dual-list loop (pass + connect, 2+2 unroll -> 4 loads in flight across
// both lists), drained by the 4-unroll helper. Residual/out nontemporal.
// ===========================================================================
__device__ __forceinline__ void gacc16(const ushort* __restrict__ Y,
                                       const int* __restrict__ es, int e0,
                                       int e1, int c8, float* a) {
  int e = e0;
  for (; e + 3 < e1; e += 4) {
    uint4 v0 = *(const uint4*)(Y + (long)es[e] * H_DIM + c8);
    uint4 v1 = *(const uint4*)(Y + (long)es[e + 1] * H_DIM + c8);
    uint4 v2 = *(const uint4*)(Y + (long)es[e + 2] * H_DIM + c8);
    uint4 v3 = *(const uint4*)(Y + (long)es[e + 3] * H_DIM + c8);
    a[0] += (bflo(v0.x) + bflo(v1.x)) + (bflo(v2.x) + bflo(v3.x));
    a[1] += (bfhi(v0.x) + bfhi(v1.x)) + (bfhi(v2.x) + bfhi(v3.x));
    a[2] += (bflo(v0.y) + bflo(v1.y)) + (bflo(v2.y) + bflo(v3.y));
    a[3] += (bfhi(v0.y) + bfhi(v1.y)) + (bfhi(v2.y) + bfhi(v3.y));
    a[4] += (bflo(v0.z) + bflo(v1.z)) + (bflo(v2.z) + bflo(v3.z));
    a[5] += (bfhi(v0.z) + bfhi(v1.z)) + (bfhi(v2.z) + bfhi(v3.z));
    a[6] += (bflo(v0.w) + bflo(v1.w)) + (bflo(v2.w) + bflo(v3.w));
    a[7] += (bfhi(v0.w) + bfhi(v1.w)) + (bfhi(v2.w) + bfhi(v3.w));
  }
  for (; e < e1; ++e) {
    uint4 v = *(const uint4*)(Y + (long)es[e] * H_DIM + c8);
    a[0] += bflo(v.x);
    a[1] += bfhi(v.x);
    a[2] += bflo(v.y);
    a[3] += bfhi(v.y);
    a[4] += bflo(v.z);
    a[5] += bfhi(v.z);
    a[6] += bflo(v.w);
    a[7] += bfhi(v.w);
  }
}

__global__ __launch_bounds__(256) void gather_k(
    const ushort* __restrict__ Y1, const ushort* __restrict__ Y2,
    const ushort* __restrict__ Yp, const int* __restrict__ ro,
    const int* __restrict__ bscan, const int* __restrict__ es,
    const float* __restrict__ rf, const float* __restrict__ pf,
    const float* __restrict__ b_r, const float* __restrict__ b_p,
    float* __restrict__ out_r, float* __restrict__ out_p, int nrb, int NRn,
    int NPn, int nseg, int Etot) {
  int tid = threadIdx.x;
  int lane = tid & 63;
  int wv = tid >> 6;
  int sub = lane >> 4;       // 0..3: subrow within wave
  int c8 = (lane & 15) * 8;  // col offset (8 floats)
  int bid = blockIdx.x;

  if (bid < nrb) {
    int row = bid * 16 + wv * 4 + sub;
    if (row >= NRn) return;
    const f32x4* rp = (const f32x4*)&rf[(long)row * H_DIM + c8];
    f32x4 rv0 = __builtin_nontemporal_load(rp);
    f32x4 rv1 = __builtin_nontemporal_load(rp + 1);
    float4 bb0 = *(const float4*)&b_r[c8];
    float4 bb1 = *(const float4*)&b_r[c8 + 4];
    int sA = ro[row] + bscan[row >> 11];
    int eA = ro[row + 1] + bscan[(row + 1) >> 11];
    int sB = ro[NRn + row] + bscan[(NRn + row) >> 11];
    int eB = ro[NRn + row + 1] + bscan[(NRn + row + 1) >> 11];
    float a[8] = {0.f, 0.f, 0.f, 0.f, 0.f, 0.f, 0.f, 0.f};
    float c[8] = {0.f, 0.f, 0.f, 0.f, 0.f, 0.f, 0.f, 0.f};
    int ea = sA, eb = sB;
    for (; ea + 1 < eA && eb + 1 < eB; ea += 2, eb += 2) {
      uint4 va0 = *(const uint4*)(Y1 + (long)es[ea] * H_DIM + c8);
      uint4 va1 = *(const uint4*)(Y1 + (long)es[ea + 1] * H_DIM + c8);
      uint4 vb0 = *(const uint4*)(Y2 + (long)es[eb] * H_DIM + c8);
      uint4 vb1 = *(const uint4*)(Y2 + (long)es[eb + 1] * H_DIM + c8);
      a[0] += bflo(va0.x) + bflo(va1.x);
      a[1] += bfhi(va0.x) + bfhi(va1.x);
      a[2] += bflo(va0.y) + bflo(va1.y);
      a[3] += bfhi(va0.y) + bfhi(va1.y);
      a[4] += bflo(va0.z) + bflo(va1.z);
      a[5] += bfhi(va0.z) + bfhi(va1.z);
      a[6] += bflo(va0.w) + bflo(va1.w);
      a[7] += bfhi(va0.w) + bfhi(va1.w);
      c[0] += bflo(vb0.x) + bflo(vb1.x);
      c[1] += bfhi(vb0.x) + bfhi(vb1.x);
      c[2] += bflo(vb0.y) + bflo(vb1.y);
      c[3] += bfhi(vb0.y) + bfhi(vb1.y);
      c[4] += bflo(vb0.z) + bflo(vb1.z);
      c[5] += bfhi(vb0.z) + bfhi(vb1.z);
      c[6] += bflo(vb0.w) + bflo(vb1.w);
      c[7] += bfhi(vb0.w) + bfhi(vb1.w);
    }
    gacc16(Y1, es, ea, eA, c8, a);
    gacc16(Y2, es, eb, eB, c8, c);
    float bv[8] = {bb0.x, bb0.y, bb0.z, bb0.w, bb1.x, bb1.y, bb1.z, bb1.w};
    f32x4 o0, o1;
#pragma unroll
    for (int i = 0; i < 4; ++i) {
      float v = (a[i] + c[i]) + bv[i];
      v = v > 0.f ? v : 0.f;
      o0[i] = rv0[i] + v;
      float v2 = (a[i + 4] + c[i + 4]) + bv[i + 4];
      v2 = v2 > 0.f ? v2 : 0.f;
      o1[i] = rv1[i] + v2;
    }
    f32x4* op = (f32x4*)&out_r[(long)row * H_DIM + c8];
    __builtin_nontemporal_store(o0, op);
    __builtin_nontemporal_store(o1, op + 1);
  } else {
    int row = (bid - nrb) * 16 + wv * 4 + sub;
    if (row >= NPn) return;
    const f32x4* pp = (const f32x4*)&pf[(long)row * H_DIM + c8];
    f32x4 pv0 = __builtin_nontemporal_load(pp);
    f32x4 pv1 = __builtin_nontemporal_load(pp + 1);
    float4 bb0 = *(const float4*)&b_p[c8];
    float4 bb1 = *(const float4*)&b_p[c8 + 4];
    int s = 2 * NRn + row;
    int e0 = ro[s] + bscan[s >> 11];
    int e1 =
        (s + 1 == nseg) ? Etot : ro[s + 1] + bscan[(s + 1) >> 11];
    float a[8] = {0.f, 0.f, 0.f, 0.f, 0.f, 0.f, 0.f, 0.f};
    gacc16(Yp, es, e0, e1, c8, a);
    int deg = e1 - e0;
    float inv = 1.0f / (float)(deg > 1 ? deg : 1);
    float bv[8] = {bb0.x, bb0.y, bb0.z, bb0.w, bb1.x, bb1.y, bb1.z, bb1.w};
    f32x4 o0, o1;
#pragma unroll
    for (int i = 0; i < 4; ++i) {
      float v = a[i] * inv + bv[i];
      v = v > 0.f ? v : 0.f;
      o0[i] = pv0[i] + v;
      float v2 = a[i + 4] * inv + bv[i + 4];
      v2 = v2 > 0.f ? v2 : 0.f;
      o1[i] = pv1[i] + v2;
    }
    f32x4* op = (f32x4*)&out_p[(long)row * H_DIM + c8];
    __builtin_nontemporal_store(o0, op);
    __builtin_nontemporal_store(o1, op + 1);
  }
}

extern "C" void kernel_launch(void* const* d_in, const int* in_sizes, int n_in,
                              void* d_out, int out_size, void* d_ws,
                              size_t ws_size, hipStream_t stream) {
  const float* router_feat = (const float*)d_in[0];
  const float* packet_feat = (const float*)d_in[1];
  const float* W_r = (const float*)d_in[2];
  const float* b_r = (const float*)d_in[3];
  const float* W_p = (const float*)d_in[4];
  const float* b_p = (const float*)d_in[5];
  const int* pass_src = (const int*)d_in[6];
  const int* pass_dst = (const int*)d_in[7];
  const int* connect_src = (const int*)d_in[8];
  const int* connect_dst = (const int*)d_in[9];
  const int* transfer_src = (const int*)d_in[10];
  const int* transfer_dst = (const int*)d_in[11];

  const int NRn = in_sizes[0] / H_DIM;  // 100000
  const int NPn = in_sizes[1] / H_DIM;  // 200000
  const int E0 = in_sizes[6], E1 = in_sizes[8], E2 = in_sizes[10];
  const long Etot = (long)E0 + E1 + E2;
  const int nseg = 2 * NRn + NPn;

  float* out_r = (float*)d_out;
  float* out_p = out_r + (size_t)NRn * H_DIM;

  // ws ints: [ro nseg+1][cnt 1][bsums 256][bscan 256][rank Etot][es Etot]
  int* ro = (int*)d_ws;
  int* cnt = ro + (nseg + 1);
  int* bsums = cnt + 1;
  int* bscan = bsums + 256;
  int* rank = bscan + 256;
  int* es = rank + Etot;
  size_t int_count = (size_t)(nseg + 1) + 1 + 512 + 2 * (size_t)Etot;
  size_t byte_off = ((int_count * 4) + 15) & ~(size_t)15;
  ushort* Y1 = (ushort*)((char*)d_ws + byte_off);
  ushort* Y2 = Y1 + (size_t)NRn * H_DIM;
  ushort* Yp = Y2 + (size_t)NPn * H_DIM;
  ushort* Wt = Yp + (size_t)NRn * H_DIM;  // 3*16384

  // zero ro + cnt in one memset
  (void)hipMemsetAsync(ro, 0, (size_t)(nseg + 2) * sizeof(int), stream);

  int egrid = (int)((Etot + 255) / 256);
  histcast_k<<<192 + egrid, 256, 0, stream>>>(W_r, W_p, Wt, pass_dst,
                                              connect_dst, transfer_dst, ro,
                                              rank, E0, E1, E2, NRn);
  int nb = (nseg + 2047) / 2048;
  scan1_k<<<nb, 256, 0, stream>>>(ro, nseg, bsums, bscan, cnt, nb);

  int nb1 = (NRn + 127) / 128, nb2 = (NPn + 127) / 128, nb3 = nb1;
  int ng = nb1 + nb2 + nb3;
  int np = egrid;
  permgemm_k<<<ng + np, 256, 0, stream>>>(
      router_feat, packet_feat, Wt, Y1, Y2, Yp, pass_src, pass_dst, connect_src,
      connect_dst, transfer_src, transfer_dst, ro, bscan, rank, es, nb1, nb2,
      NRn, NPn, E0, E1, E2, NRn, ng, np);

  int nrb = (NRn + 15) / 16, npb = (NPn + 15) / 16;
  gather_k<<<nrb + npb, 256, 0, stream>>>(
      Y1, Y2, Yp, ro, bscan, es, router_feat, packet_feat, b_r, b_p, out_r,
      out_p, nrb, NRn, NPn, nseg, (int)Etot);
}

// Round 11
// 311.496 us; speedup vs baseline: 1.0904x; 1.0904x over previous
//
#include <hip/hip_runtime.h>
#include <hip/hip_bf16.h>

#define H_DIM 128

typedef __attribute__((ext_vector_type(8))) short short8v;
typedef __attribute__((ext_vector_type(4))) float f32x4;

// HW bf16 conversion (compiler emits v_cvt_pk_bf16_f32 pairs) -- the old
// integer-RNE emulation cost ~4 VALU inst/elem and dominated the GEMM.
__device__ __forceinline__ ushort f2bf(float f) {
  __hip_bfloat16 b = __float2bfloat16(f);
  return __builtin_bit_cast(ushort, b);
}
__device__ __forceinline__ float bflo(unsigned u) {
  return __builtin_bit_cast(float, u << 16);
}
__device__ __forceinline__ float bfhi(unsigned u) {
  return __builtin_bit_cast(float, u & 0xffff0000u);
}
__device__ __forceinline__ short8v pack_bf8(float4 a0, float4 a1) {
  short8v af;
  af[0] = (short)f2bf(a0.x);
  af[1] = (short)f2bf(a0.y);
  af[2] = (short)f2bf(a0.z);
  af[3] = (short)f2bf(a0.w);
  af[4] = (short)f2bf(a1.x);
  af[5] = (short)f2bf(a1.y);
  af[6] = (short)f2bf(a1.z);
  af[7] = (short)f2bf(a1.w);
  return af;
}

// ===========================================================================
// Fused: weight cast/transpose (blocks 0..191) + concatenated histogram.
// Histogram atomic's return value = edge rank (atomic-free permute later).
// Wt[m][j][k] = W[k][j]; m=0: W_r[0:128], m=1: W_r[128:256], m=2: W_p.
// ===========================================================================
__global__ __launch_bounds__(256) void histcast_k(
    const float* __restrict__ W_r, const float* __restrict__ W_p,
    ushort* __restrict__ Wt, const int* __restrict__ d0,
    const int* __restrict__ d1, const int* __restrict__ d2,
    int* __restrict__ ro, int* __restrict__ rank, int n0, int n1, int n2,
    int NRn) {
  int bid = blockIdx.x;
  if (bid < 192) {
    int i = bid * 256 + threadIdx.x;
    int m = i >> 14;
    int j = (i >> 7) & 127;
    int k = i & 127;
    float v = (m == 0)   ? W_r[k * 128 + j]
              : (m == 1) ? W_r[(128 + k) * 128 + j]
                         : W_p[k * 128 + j];
    Wt[i] = f2bf(v);
  } else {
    int e = (bid - 192) * 256 + threadIdx.x;
    int slot;
    if (e < n0)
      slot = d0[e];
    else if (e < n0 + n1)
      slot = NRn + d1[e - n0];
    else if (e < n0 + n1 + n2)
      slot = 2 * NRn + d2[e - n0 - n1];
    else
      return;
    rank[e] = atomicAdd(&ro[slot], 1);
  }
}

// Per-block (2048 elems) exclusive scan in-place; block sums -> bsums.
__global__ __launch_bounds__(256) void scan1_k(int* __restrict__ a, int n,
                                               int* __restrict__ bsums) {
  __shared__ int ts[256];
  int t = threadIdx.x;
  int base = blockIdx.x * 2048 + t * 8;
  int v[8];
  int s = 0;
#pragma unroll
  for (int k = 0; k < 8; ++k) {
    v[k] = (base + k < n) ? a[base + k] : 0;
    s += v[k];
  }
  ts[t] = s;
  __syncthreads();
  for (int off = 1; off < 256; off <<= 1) {
    int x = (t >= off) ? ts[t - off] : 0;
    __syncthreads();
    ts[t] += x;
    __syncthreads();
  }
  if (t == 0) bsums[blockIdx.x] = ts[255];
  int run = (t == 0) ? 0 : ts[t - 1];
#pragma unroll
  for (int k = 0; k < 8; ++k) {
    int x = v[k];
    if (base + k < n) a[base + k] = run;
    run += x;
  }
}

// Merged scan2+scan3: every block redundantly scans bsums (nb<=256) in LDS,
// then adds its block's exclusive offset to its 2048 elements.
__global__ __launch_bounds__(256) void scan23_k(int* __restrict__ a, int n,
                                                const int* __restrict__ bsums,
                                                int nb, int total) {
  __shared__ int ts[256];
  int t = threadIdx.x;
  int v = (t < nb) ? bsums[t] : 0;
  ts[t] = v;
  __syncthreads();
  for (int off = 1; off < 256; off <<= 1) {
    int x = (t >= off) ? ts[t - off] : 0;
    __syncthreads();
    ts[t] += x;
    __syncthreads();
  }
  int b = blockIdx.x;
  int excl = (b == 0) ? 0 : ts[b - 1];
  int base = b * 2048;
#pragma unroll
  for (int k = 0; k < 8; ++k) {
    int i = base + k * 256 + t;
    if (i < n) a[i] += excl;
  }
  if (b == 0 && t == 0) a[n] = total;
}

// ===========================================================================
// Fused: dense GEMM (M-tile 128, two row-tiles per wave SHARING each
// B-fragment -> 16 MFMA per 8 ds_read_b128) + atomic-free edge permute,
// proportionally interleaved. 32KB LDS keeps occupancy.
// ===========================================================================
__global__ __launch_bounds__(256) void permgemm_k(
    const float* __restrict__ rf, const float* __restrict__ pf,
    const ushort* __restrict__ Wt, ushort* __restrict__ Y1,
    ushort* __restrict__ Y2, ushort* __restrict__ Yp,
    const int* __restrict__ s0a, const int* __restrict__ d0a,
    const int* __restrict__ s1a, const int* __restrict__ d1a,
    const int* __restrict__ s2a, const int* __restrict__ d2a,
    const int* __restrict__ ro, const int* __restrict__ rank,
    int* __restrict__ es, int nb1, int nb2, int M1, int M2, int n0, int n1,
    int n2, int NRn, int ng, int np) {
  __shared__ float lds_f[8192];  // 32KB
  long T = (long)ng + np;
  long b = blockIdx.x;
  int g_before = (int)((b * ng) / T);
  int g_incl = (int)(((b + 1) * ng) / T);
  bool do_gemm = g_incl > g_before;
  int idx = do_gemm ? g_before : (int)(b - g_before);

  if (!do_gemm) {
    long e = (long)idx * 256 + threadIdx.x;
    int src, slot;
    if (e < n0) {
      slot = d0a[e];
      src = s0a[e];
    } else if (e < n0 + n1) {
      long i = e - n0;
      slot = NRn + d1a[i];
      src = s1a[i];
    } else if (e < n0 + n1 + n2) {
      long i = e - n0 - n1;
      slot = 2 * NRn + d2a[i];
      src = s2a[i];
    } else
      return;
    es[ro[slot] + rank[e]] = src;
    return;
  }

  ushort* wl = (ushort*)lds_f;
  const float* X;
  ushort* Y;
  const ushort* Wg;
  int M, row0;
  if (idx < nb1) {
    X = rf; Y = Y1; Wg = Wt; M = M1; row0 = idx * 128;
  } else if (idx < nb1 + nb2) {
    X = pf; Y = Y2; Wg = Wt + 16384; M = M2; row0 = (idx - nb1) * 128;
  } else {
    X = rf; Y = Yp; Wg = Wt + 32768; M = M1; row0 = (idx - nb1 - nb2) * 128;
  }

  int tid = threadIdx.x;
  {  // stage W -> LDS, XOR swizzle on 8-ushort granularity
    const uint4* src = (const uint4*)Wg;
    for (int i = tid; i < 2048; i += 256) {
      int j = i >> 4;
      int k8 = (i & 15) * 8;
      int kk = k8 ^ ((j & 7) << 3);
      *(uint4*)&wl[j * 128 + kk] = src[i];
    }
  }
  __syncthreads();

  int lane = tid & 63;
  int wv = tid >> 6;
  int l15 = lane & 15;
  int kq = lane >> 4;
  int rowl = wv * 16 + l15;
  int g0 = row0 + rowl;
  int g1 = row0 + 64 + rowl;
  int gc0 = g0 < M ? g0 : M - 1;
  int gc1 = g1 < M ? g1 : M - 1;

  f32x4 acc0[8], acc1[8];
#pragma unroll
  for (int t = 0; t < 8; ++t) {
    f32x4 z = {0.f, 0.f, 0.f, 0.f};
    acc0[t] = z;
    acc1[t] = z;
  }

#pragma unroll
  for (int ks = 0; ks < 4; ++ks) {
    int k0 = ks * 32;
    const float* ap0 = X + (long)gc0 * H_DIM + k0 + kq * 8;
    const float* ap1 = X + (long)gc1 * H_DIM + k0 + kq * 8;
    float4 a00 = *(const float4*)ap0;
    float4 a01 = *(const float4*)(ap0 + 4);
    float4 a10 = *(const float4*)ap1;
    float4 a11 = *(const float4*)(ap1 + 4);
    short8v af0 = pack_bf8(a00, a01);
    short8v af1 = pack_bf8(a10, a11);
#pragma unroll
    for (int nt = 0; nt < 8; ++nt) {
      int j = nt * 16 + l15;
      int kk = (k0 + kq * 8) ^ ((j & 7) << 3);
      short8v bf = *(const short8v*)&wl[j * 128 + kk];
      acc0[nt] =
          __builtin_amdgcn_mfma_f32_16x16x32_bf16(af0, bf, acc0[nt], 0, 0, 0);
      acc1[nt] =
          __builtin_amdgcn_mfma_f32_16x16x32_bf16(af1, bf, acc1[nt], 0, 0, 0);
    }
  }

  // ---- epilogue pass 0: rows [row0, row0+64) ----
  __syncthreads();
#pragma unroll
  for (int nt = 0; nt < 8; ++nt) {
#pragma unroll
    for (int r = 0; r < 4; ++r) {
      int rl = wv * 16 + kq * 4 + r;
      int col = (nt * 16 + l15) ^ (kq << 4);
      lds_f[rl * 128 + col] = acc0[nt][r];
    }
  }
  __syncthreads();
  for (int i = tid; i < 2048; i += 256) {
    int flat = i * 4;
    int r = flat >> 7;
    int cc = flat & 127;
    int sw = ((r >> 2) & 3) << 4;
    int gr = row0 + r;
    if (gr < M) {
      float4 v = *(const float4*)&lds_f[r * 128 + (cc ^ sw)];
      ushort4 o;
      o.x = f2bf(v.x);
      o.y = f2bf(v.y);
      o.z = f2bf(v.z);
      o.w = f2bf(v.w);
      *(ushort4*)&Y[(long)gr * H_DIM + cc] = o;
    }
  }
  // ---- epilogue pass 1: rows [row0+64, row0+128) ----
  __syncthreads();
#pragma unroll
  for (int nt = 0; nt < 8; ++nt) {
#pragma unroll
    for (int r = 0; r < 4; ++r) {
      int rl = wv * 16 + kq * 4 + r;
      int col = (nt * 16 + l15) ^ (kq << 4);
      lds_f[rl * 128 + col] = acc1[nt][r];
    }
  }
  __syncthreads();
  for (int i = tid; i < 2048; i += 256) {
    int flat = i * 4;
    int r = flat >> 7;
    int cc = flat & 127;
    int sw = ((r >> 2) & 3) << 4;
    int gr = row0 + 64 + r;
    if (gr < M) {
      float4 v = *(const float4*)&lds_f[r * 128 + (cc ^ sw)];
      ushort4 o;
      o.x = f2bf(v.x);
      o.y = f2bf(v.y);
      o.z = f2bf(v.z);
      o.w = f2bf(v.w);
      *(ushort4*)&Y[(long)gr * H_DIM + cc] = o;
    }
  }
}

// ===========================================================================
// Gather: 16 lanes/row, uint4 (8 bf16)/lane, 4-edge unroll; residual/bias
// hoisted above the edge loops; router's two segment-sums use independent
// accumulators. Residual/out traffic nontemporal.
// ===========================================================================
__device__ __forceinline__ void gacc16(const ushort* __restrict__ Y,
                                       const int* __restrict__ es, int e0,
                                       int e1, int c8, float* a) {
  int e = e0;
  for (; e + 3 < e1; e += 4) {
    uint4 v0 = *(const uint4*)(Y + (long)es[e] * H_DIM + c8);
    uint4 v1 = *(const uint4*)(Y + (long)es[e + 1] * H_DIM + c8);
    uint4 v2 = *(const uint4*)(Y + (long)es[e + 2] * H_DIM + c8);
    uint4 v3 = *(const uint4*)(Y + (long)es[e + 3] * H_DIM + c8);
    a[0] += (bflo(v0.x) + bflo(v1.x)) + (bflo(v2.x) + bflo(v3.x));
    a[1] += (bfhi(v0.x) + bfhi(v1.x)) + (bfhi(v2.x) + bfhi(v3.x));
    a[2] += (bflo(v0.y) + bflo(v1.y)) + (bflo(v2.y) + bflo(v3.y));
    a[3] += (bfhi(v0.y) + bfhi(v1.y)) + (bfhi(v2.y) + bfhi(v3.y));
    a[4] += (bflo(v0.z) + bflo(v1.z)) + (bflo(v2.z) + bflo(v3.z));
    a[5] += (bfhi(v0.z) + bfhi(v1.z)) + (bfhi(v2.z) + bfhi(v3.z));
    a[6] += (bflo(v0.w) + bflo(v1.w)) + (bflo(v2.w) + bflo(v3.w));
    a[7] += (bfhi(v0.w) + bfhi(v1.w)) + (bfhi(v2.w) + bfhi(v3.w));
  }
  for (; e < e1; ++e) {
    uint4 v = *(const uint4*)(Y + (long)es[e] * H_DIM + c8);
    a[0] += bflo(v.x);
    a[1] += bfhi(v.x);
    a[2] += bflo(v.y);
    a[3] += bfhi(v.y);
    a[4] += bflo(v.z);
    a[5] += bfhi(v.z);
    a[6] += bflo(v.w);
    a[7] += bfhi(v.w);
  }
}

__global__ __launch_bounds__(256) void gather_k(
    const ushort* __restrict__ Y1, const ushort* __restrict__ Y2,
    const ushort* __restrict__ Yp, const int* __restrict__ ro,
    const int* __restrict__ es, const float* __restrict__ rf,
    const float* __restrict__ pf, const float* __restrict__ b_r,
    const float* __restrict__ b_p, float* __restrict__ out_r,
    float* __restrict__ out_p, int nrb, int NRn, int NPn) {
  int tid = threadIdx.x;
  int lane = tid & 63;
  int wv = tid >> 6;
  int sub = lane >> 4;       // 0..3: subrow within wave
  int c8 = (lane & 15) * 8;  // col offset (8 floats)
  int bid = blockIdx.x;

  if (bid < nrb) {
    int row = bid * 16 + wv * 4 + sub;
    if (row >= NRn) return;
    const f32x4* rp = (const f32x4*)&rf[(long)row * H_DIM + c8];
    f32x4 rv0 = __builtin_nontemporal_load(rp);
    f32x4 rv1 = __builtin_nontemporal_load(rp + 1);
    float4 bb0 = *(const float4*)&b_r[c8];
    float4 bb1 = *(const float4*)&b_r[c8 + 4];
    float a[8] = {0.f, 0.f, 0.f, 0.f, 0.f, 0.f, 0.f, 0.f};
    float c[8] = {0.f, 0.f, 0.f, 0.f, 0.f, 0.f, 0.f, 0.f};
    gacc16(Y1, es, ro[row], ro[row + 1], c8, a);
    gacc16(Y2, es, ro[NRn + row], ro[NRn + row + 1], c8, c);
    float bv[8] = {bb0.x, bb0.y, bb0.z, bb0.w, bb1.x, bb1.y, bb1.z, bb1.w};
    f32x4 o0, o1;
#pragma unroll
    for (int i = 0; i < 4; ++i) {
      float v = (a[i] + c[i]) + bv[i];
      v = v > 0.f ? v : 0.f;
      o0[i] = rv0[i] + v;
      float v2 = (a[i + 4] + c[i + 4]) + bv[i + 4];
      v2 = v2 > 0.f ? v2 : 0.f;
      o1[i] = rv1[i] + v2;
    }
    f32x4* op = (f32x4*)&out_r[(long)row * H_DIM + c8];
    __builtin_nontemporal_store(o0, op);
    __builtin_nontemporal_store(o1, op + 1);
  } else {
    int row = (bid - nrb) * 16 + wv * 4 + sub;
    if (row >= NPn) return;
    const f32x4* pp = (const f32x4*)&pf[(long)row * H_DIM + c8];
    f32x4 pv0 = __builtin_nontemporal_load(pp);
    f32x4 pv1 = __builtin_nontemporal_load(pp + 1);
    float4 bb0 = *(const float4*)&b_p[c8];
    float4 bb1 = *(const float4*)&b_p[c8 + 4];
    int e0 = ro[2 * NRn + row], e1 = ro[2 * NRn + row + 1];
    float a[8] = {0.f, 0.f, 0.f, 0.f, 0.f, 0.f, 0.f, 0.f};
    gacc16(Yp, es, e0, e1, c8, a);
    int deg = e1 - e0;
    float inv = 1.0f / (float)(deg > 1 ? deg : 1);
    float bv[8] = {bb0.x, bb0.y, bb0.z, bb0.w, bb1.x, bb1.y, bb1.z, bb1.w};
    f32x4 o0, o1;
#pragma unroll
    for (int i = 0; i < 4; ++i) {
      float v = a[i] * inv + bv[i];
      v = v > 0.f ? v : 0.f;
      o0[i] = pv0[i] + v;
      float v2 = a[i + 4] * inv + bv[i + 4];
      v2 = v2 > 0.f ? v2 : 0.f;
      o1[i] = pv1[i] + v2;
    }
    f32x4* op = (f32x4*)&out_p[(long)row * H_DIM + c8];
    __builtin_nontemporal_store(o0, op);
    __builtin_nontemporal_store(o1, op + 1);
  }
}

extern "C" void kernel_launch(void* const* d_in, const int* in_sizes, int n_in,
                              void* d_out, int out_size, void* d_ws,
                              size_t ws_size, hipStream_t stream) {
  const float* router_feat = (const float*)d_in[0];
  const float* packet_feat = (const float*)d_in[1];
  const float* W_r = (const float*)d_in[2];
  const float* b_r = (const float*)d_in[3];
  const float* W_p = (const float*)d_in[4];
  const float* b_p = (const float*)d_in[5];
  const int* pass_src = (const int*)d_in[6];
  const int* pass_dst = (const int*)d_in[7];
  const int* connect_src = (const int*)d_in[8];
  const int* connect_dst = (const int*)d_in[9];
  const int* transfer_src = (const int*)d_in[10];
  const int* transfer_dst = (const int*)d_in[11];

  const int NRn = in_sizes[0] / H_DIM;  // 100000
  const int NPn = in_sizes[1] / H_DIM;  // 200000
  const int E0 = in_sizes[6], E1 = in_sizes[8], E2 = in_sizes[10];
  const long Etot = (long)E0 + E1 + E2;
  const int nseg = 2 * NRn + NPn;

  float* out_r = (float*)d_out;
  float* out_p = out_r + (size_t)NRn * H_DIM;

  // workspace: [ro nseg+1][rank Etot][es Etot][bsums 256] | Y1 Y2 Yp Wt
  int* ro = (int*)d_ws;
  int* rank = ro + (nseg + 1);
  int* es = rank + Etot;
  int* bsums = es + Etot;
  size_t int_count = (size_t)(nseg + 1) + 2 * (size_t)Etot + 256;
  size_t byte_off = ((int_count * 4) + 15) & ~(size_t)15;
  ushort* Y1 = (ushort*)((char*)d_ws + byte_off);
  ushort* Y2 = Y1 + (size_t)NRn * H_DIM;
  ushort* Yp = Y2 + (size_t)NPn * H_DIM;
  ushort* Wt = Yp + (size_t)NRn * H_DIM;  // 3*16384

  (void)hipMemsetAsync(ro, 0, (size_t)(nseg + 1) * sizeof(int), stream);

  int egrid = (int)((Etot + 255) / 256);
  histcast_k<<<192 + egrid, 256, 0, stream>>>(W_r, W_p, Wt, pass_dst,
                                              connect_dst, transfer_dst, ro,
                                              rank, E0, E1, E2, NRn);
  int nb = (nseg + 2047) / 2048;
  scan1_k<<<nb, 256, 0, stream>>>(ro, nseg, bsums);
  scan23_k<<<nb, 256, 0, stream>>>(ro, nseg, bsums, nb, (int)Etot);

  int nb1 = (NRn + 127) / 128, nb2 = (NPn + 127) / 128, nb3 = nb1;
  int ng = nb1 + nb2 + nb3;
  int np = egrid;
  permgemm_k<<<ng + np, 256, 0, stream>>>(
      router_feat, packet_feat, Wt, Y1, Y2, Yp, pass_src, pass_dst, connect_src,
      connect_dst, transfer_src, transfer_dst, ro, rank, es, nb1, nb2, NRn, NPn,
      E0, E1, E2, NRn, ng, np);

  int nrb = (NRn + 15) / 16, npb = (NPn + 15) / 16;
  gather_k<<<nrb + npb, 256, 0, stream>>>(Y1, Y2, Yp, ro, es, router_feat,
                                          packet_feat, b_r, b_p, out_r, out_p,
                                          nrb, NRn, NPn);
}